// Round 4
// baseline (243.190 us; speedup 1.0000x reference)
//
#include <hip/hip_runtime.h>
#include <hip/hip_bf16.h>

#define IN_FEATS 602
#define N_HIDDEN 256
#define N_CLASSES 41
#define N_SRC0 292864
#define N_DST0 11264
#define N_DST1 1024
#define FAN0 25
#define FAN1 10
#define KPAD 1216            // 1204 rounded up to multiple of 32 (38 K-steps)
#define MT 16                // dst rows per fused block
#define ALDS 1224            // LDS row stride in bf16 (2448 B, 16B-aligned rows)

typedef __attribute__((ext_vector_type(4))) float f32x4;
typedef __attribute__((ext_vector_type(8))) short bf16x8;   // 8 bf16 = 4 VGPRs

// round-to-nearest-even f32 -> bf16, packed pair
static __device__ __forceinline__ unsigned pack_bf16x2(float lo, float hi) {
    unsigned a = __float_as_uint(lo);
    unsigned b = __float_as_uint(hi);
    a = (a + 0x7fffu + ((a >> 16) & 1u)) >> 16;
    b = (b + 0x7fffu + ((b >> 16) & 1u)) >> 16;
    return (a & 0xffffu) | (b << 16);
}

// ---------------------------------------------------------------------------
// Kernel 1: Wt[n][k] = bf16( k<602 ? Wself0[k][n] : k<1204 ? Wneigh0[k-602][n] : 0 )
// Wt is [N_HIDDEN][KPAD] bf16 (B pre-transposed, K-major). Unchanged from R3.
// ---------------------------------------------------------------------------
__global__ __launch_bounds__(256) void wprep_kernel(
    const float* __restrict__ Ws,
    const float* __restrict__ Wn,
    __hip_bfloat16* __restrict__ Wt)
{
    __shared__ float tile[32][33];
    const int k0 = blockIdx.x * 32, n0 = blockIdx.y * 32;
    const int tx = threadIdx.x & 31, ty = threadIdx.x >> 5;   // 32 x 8

    #pragma unroll
    for (int i = 0; i < 4; ++i) {
        const int k = k0 + ty + i * 8;
        const int n = n0 + tx;
        float v = 0.f;
        if (k < IN_FEATS)            v = Ws[(size_t)k * N_HIDDEN + n];
        else if (k < 2 * IN_FEATS)   v = Wn[(size_t)(k - IN_FEATS) * N_HIDDEN + n];
        tile[ty + i * 8][tx] = v;
    }
    __syncthreads();
    #pragma unroll
    for (int i = 0; i < 4; ++i) {
        const int n = n0 + ty + i * 8;
        const int k = k0 + tx;
        Wt[(size_t)n * KPAD + k] = __float2bfloat16(tile[tx][ty + i * 8]);
    }
}

// ---------------------------------------------------------------------------
// Kernel 2 (FUSED gather + convert + GEMM):
//   per block: 16 dst rows. Phase 1: 4 waves x 4 dsts gather 25 neighbors,
//   mean in f32, pack bf16 -> LDS A-tile [16][1224] = [self|neigh|0pad].
//   Phase 2: h[16 x 256] = relu(A @ Wt^T + b0) via MFMA; B streamed from
//   L2-resident Wt with 2-deep register prefetch. A never touches HBM.
// ---------------------------------------------------------------------------
__global__ __launch_bounds__(256) void fused0_kernel(
    const float* __restrict__ x,       // [N_SRC0][602] f32
    const int* __restrict__ idx0,      // [N_DST0*25]
    const __hip_bfloat16* __restrict__ Wt,   // [256][KPAD]
    const float* __restrict__ bias,    // [256]
    float* __restrict__ h)             // [N_DST0][256]
{
    __shared__ __hip_bfloat16 Atile[MT][ALDS];   // 39.2 KB

    const int tid  = threadIdx.x;
    const int lane = tid & 63;
    const int w    = tid >> 6;         // wave 0..3
    const int r    = lane & 15;
    const int g    = lane >> 4;

    // ---- phase 1: gather ----
    #pragma unroll
    for (int s = 0; s < 4; ++s) {
        const int local = w * 4 + s;                 // LDS row 0..15
        const int d = blockIdx.x * MT + local;       // dst node
        const int* ip = idx0 + d * FAN0;

        int ridx[FAN0];
        #pragma unroll
        for (int n = 0; n < FAN0; ++n)
            ridx[n] = __builtin_amdgcn_readfirstlane(ip[n]);  // wave-uniform -> SGPR

        // zero pad cols 1204..1223 (10 dwords at byte 2408..2447)
        if (lane < 10)
            *(unsigned*)((char*)&Atile[local][0] + 2408 + lane * 4) = 0u;

        #pragma unroll
        for (int p = 0; p < 5; ++p) {
            const int f2 = p * 64 + lane;            // float2 index 0..300
            if (f2 <= 300) {
                const int f = f2 * 2;
                float sx = 0.f, sy = 0.f;
                #pragma unroll
                for (int n = 0; n < FAN0; ++n) {
                    const float2 v = *(const float2*)&x[(size_t)ridx[n] * IN_FEATS + f];
                    sx += v.x; sy += v.y;
                }
                const float2 sv = *(const float2*)&x[(size_t)d * IN_FEATS + f];
                // self cols f..f+1 at byte f2*4; neigh cols 602+f..603+f at byte 1204+f2*4
                *(unsigned*)((char*)&Atile[local][0] + f2 * 4) = pack_bf16x2(sv.x, sv.y);
                *(unsigned*)((char*)&Atile[local][0] + 1204 + f2 * 4) =
                    pack_bf16x2(sx * (1.0f / FAN0), sy * (1.0f / FAN0));
            }
        }
    }
    __syncthreads();

    // ---- phase 2: GEMM. wave w -> cols [w*64, w*64+64), all 16 rows ----
    const int cb = w * 64;
    f32x4 acc[4] = {};

#define LOADB(T, B) { _Pragma("unroll") \
    for (int nf = 0; nf < 4; ++nf) \
        B[nf] = *(const bf16x8*)&Wt[(size_t)(cb + nf * 16 + r) * KPAD + (T) * 32 + g * 8]; }
#define DOMFMA(T, B) { \
    const bf16x8 af = *(const bf16x8*)&Atile[r][(T) * 32 + g * 8]; \
    _Pragma("unroll") \
    for (int nf = 0; nf < 4; ++nf) \
        acc[nf] = __builtin_amdgcn_mfma_f32_16x16x32_bf16(af, B[nf], acc[nf], 0, 0, 0); }

    bf16x8 bA[4], bB[4];
    LOADB(0, bA)
    for (int t = 0; t < 36; t += 2) {      // 38 K-steps, 2-deep B prefetch
        LOADB(t + 1, bB)
        DOMFMA(t, bA)
        LOADB(t + 2, bA)
        DOMFMA(t + 1, bB)
    }
    LOADB(37, bB)
    DOMFMA(36, bA)
    DOMFMA(37, bB)
#undef LOADB
#undef DOMFMA

    // C/D layout (m89-verified): col = lane&15 (=r), row = g*4 + j
    #pragma unroll
    for (int nf = 0; nf < 4; ++nf) {
        const int col = cb + nf * 16 + r;
        const float bv = bias[col];
        #pragma unroll
        for (int j = 0; j < 4; ++j) {
            const int row = blockIdx.x * MT + g * 4 + j;
            h[(size_t)row * N_HIDDEN + col] = fmaxf(acc[nf][j] + bv, 0.f);
        }
    }
}

// ---------------------------------------------------------------------------
// Kernel 3 (fused agg1 + layer1):
// out[d] = h[d] @ Wself1 + (mean_10 h[idx1]) @ Wneigh1 + b1     (f32)
// ---------------------------------------------------------------------------
__global__ __launch_bounds__(64) void tail_kernel(
    const float* __restrict__ h,
    const int* __restrict__ idx1,
    const float* __restrict__ Ws,     // [256][41]
    const float* __restrict__ Wn,     // [256][41]
    const float* __restrict__ b,      // [41]
    float* __restrict__ out)          // [1024][41]
{
    const int d = blockIdx.x;
    __shared__ float hd[N_HIDDEN];
    __shared__ float hn[N_HIDDEN];
    __shared__ int sidx[FAN1];
    if (threadIdx.x < FAN1) sidx[threadIdx.x] = idx1[d * FAN1 + threadIdx.x];
    __syncthreads();

    for (int k = threadIdx.x; k < N_HIDDEN; k += 64) {
        hd[k] = h[(size_t)d * N_HIDDEN + k];
        float a = 0.f;
        #pragma unroll
        for (int i = 0; i < FAN1; ++i)
            a += h[(size_t)sidx[i] * N_HIDDEN + k];
        hn[k] = a * (1.0f / FAN1);
    }
    __syncthreads();

    if (threadIdx.x < N_CLASSES) {
        const int n = threadIdx.x;
        float a0 = b[n], a1 = 0.f, a2 = 0.f, a3 = 0.f;
        #pragma unroll 4
        for (int k = 0; k < N_HIDDEN; k += 4) {
            a0 += hd[k + 0] * Ws[(k + 0) * N_CLASSES + n] + hn[k + 0] * Wn[(k + 0) * N_CLASSES + n];
            a1 += hd[k + 1] * Ws[(k + 1) * N_CLASSES + n] + hn[k + 1] * Wn[(k + 1) * N_CLASSES + n];
            a2 += hd[k + 2] * Ws[(k + 2) * N_CLASSES + n] + hn[k + 2] * Wn[(k + 2) * N_CLASSES + n];
            a3 += hd[k + 3] * Ws[(k + 3) * N_CLASSES + n] + hn[k + 3] * Wn[(k + 3) * N_CLASSES + n];
        }
        out[(size_t)d * N_CLASSES + n] = a0 + a1 + a2 + a3;
    }
}

// ---------------------------------------------------------------------------
extern "C" void kernel_launch(void* const* d_in, const int* in_sizes, int n_in,
                              void* d_out, int out_size, void* d_ws, size_t ws_size,
                              hipStream_t stream) {
    const float* x       = (const float*)d_in[0];
    const float* Wself0  = (const float*)d_in[1];
    const float* Wneigh0 = (const float*)d_in[2];
    const float* b0      = (const float*)d_in[3];
    const float* Wself1  = (const float*)d_in[4];
    const float* Wneigh1 = (const float*)d_in[5];
    const float* b1      = (const float*)d_in[6];
    const int*   idx0    = (const int*)d_in[7];
    const int*   idx1    = (const int*)d_in[8];
    float* out = (float*)d_out;

    // ws layout: Wt bf16 [256*KPAD] (623 KB) | h f32 [11264*256] (11.5 MB)
    __hip_bfloat16* Wt = (__hip_bfloat16*)d_ws;
    float*          h  = (float*)(Wt + (size_t)N_HIDDEN * KPAD);

    wprep_kernel<<<dim3(KPAD / 32, N_HIDDEN / 32), 256, 0, stream>>>(Wself0, Wneigh0, Wt);
    fused0_kernel<<<N_DST0 / MT, 256, 0, stream>>>(x, idx0, Wt, b0, h);
    tail_kernel<<<N_DST1, 64, 0, stream>>>(h, idx1, Wself1, Wneigh1, b1, out);
}

// Round 5
// 238.451 us; speedup vs baseline: 1.0199x; 1.0199x over previous
//
#include <hip/hip_runtime.h>
#include <hip/hip_bf16.h>

#define IN_FEATS 602
#define N_HIDDEN 256
#define N_CLASSES 41
#define N_SRC0 292864
#define N_DST0 11264
#define N_DST1 1024
#define FAN0 25
#define FAN1 10
#define KPAD 1216            // 1204 rounded to 32 (38 K-steps of 32)
#define LDSW 72              // gemm LDS row stride (bf16)
#define NCHUNK 4
#define CH (N_DST0 / NCHUNK) // 2816 dsts per chunk
#define NW ((KPAD / 32) * 8)     // 304 wprep blocks
#define NGC (4 * (CH / 64))      // 176 gemm blocks per chunk
#define NAC (CH / 4)             // 704 agg blocks per chunk

typedef __attribute__((ext_vector_type(4))) float f32x4;
typedef __attribute__((ext_vector_type(8))) short bf16x8;

// round-to-nearest-even f32 -> bf16, packed pair
static __device__ __forceinline__ unsigned pack_bf16x2(float lo, float hi) {
    unsigned a = __float_as_uint(lo);
    unsigned b = __float_as_uint(hi);
    a = (a + 0x7fffu + ((a >> 16) & 1u)) >> 16;
    b = (b + 0x7fffu + ((b >> 16) & 1u)) >> 16;
    return (a & 0xffffu) | (b << 16);
}

// shared memory: union of the three roles' needs
#define SMBYTES (2 * 64 * LDSW * 2)   // 18432 B (gemm As+Bs)

// ---------------------------------------------------------------------------
// role: W transpose+concat+bf16   Wt[n][k] (K-major), pad cols zeroed
// ---------------------------------------------------------------------------
static __device__ __forceinline__ void wprep_role(
    int b, char* sm,
    const float* __restrict__ Ws, const float* __restrict__ Wn,
    __hip_bfloat16* __restrict__ Wt)
{
    float (*tile)[33] = (float(*)[33])sm;
    const int k0 = (b % (KPAD / 32)) * 32;
    const int n0 = (b / (KPAD / 32)) * 32;
    const int tx = threadIdx.x & 31, ty = threadIdx.x >> 5;   // 32 x 8

    #pragma unroll
    for (int i = 0; i < 4; ++i) {
        const int k = k0 + ty + i * 8;
        const int n = n0 + tx;
        float v = 0.f;
        if (k < IN_FEATS)            v = Ws[(size_t)k * N_HIDDEN + n];
        else if (k < 2 * IN_FEATS)   v = Wn[(size_t)(k - IN_FEATS) * N_HIDDEN + n];
        tile[ty + i * 8][tx] = v;
    }
    __syncthreads();
    #pragma unroll
    for (int i = 0; i < 4; ++i) {
        const int n = n0 + ty + i * 8;
        const int k = k0 + tx;
        Wt[(size_t)n * KPAD + k] = __float2bfloat16(tile[tx][ty + i * 8]);
    }
}

// ---------------------------------------------------------------------------
// role: gather + mean + bf16-pack  ->  A[d] = [self | neigh-mean | pad]
// 4 dsts per block (one per wave), float2 loads, 25 streams in flight.
// ---------------------------------------------------------------------------
static __device__ __forceinline__ void agg_role(
    int b, int dst0, char* sm,
    const float* __restrict__ x,
    const int* __restrict__ idx0,
    __hip_bfloat16* __restrict__ A)
{
    int (*sidx)[FAN0] = (int(*)[FAN0])sm;
    const int wave = threadIdx.x >> 6;
    const int lane = threadIdx.x & 63;
    const int d = dst0 + b * 4 + wave;

    if (lane < FAN0) sidx[wave][lane] = idx0[d * FAN0 + lane];
    __syncthreads();

    unsigned* Aself = (unsigned*)(A + (size_t)d * KPAD);
    const float* xself = x + (size_t)d * IN_FEATS;

    // zero pad cols 1204..1215 (6 dwords)
    if (lane < 6) Aself[602 + lane] = 0u;

    #pragma unroll
    for (int p = 0; p < 5; ++p) {
        const int f2 = p * 64 + lane;            // float2 index 0..300
        if (f2 <= 300) {
            const int f = f2 * 2;
            float sx = 0.f, sy = 0.f;
            #pragma unroll
            for (int n = 0; n < FAN0; ++n) {
                const float2 v = *(const float2*)&x[(size_t)sidx[wave][n] * IN_FEATS + f];
                sx += v.x; sy += v.y;
            }
            const float2 sv = *(const float2*)&xself[f];
            *(unsigned*)((char*)Aself + f2 * 4) = pack_bf16x2(sv.x, sv.y);
            *(unsigned*)((char*)Aself + 1204 + f2 * 4) =
                pack_bf16x2(sx * (1.0f / FAN0), sy * (1.0f / FAN0));
        }
    }
}

// ---------------------------------------------------------------------------
// role: h[m0:m0+2816][0:256] = relu(A @ Wt^T + b0)  (64x64 tiles, BK=64)
// ---------------------------------------------------------------------------
static __device__ __forceinline__ void gemm_role(
    int b, int dst0, char* sm,
    const __hip_bfloat16* __restrict__ A,
    const __hip_bfloat16* __restrict__ Wt,
    const float* __restrict__ bias,
    float* __restrict__ h)
{
    short* As = (short*)sm;
    short* Bs = As + 64 * LDSW;

    const int tid  = threadIdx.x;
    const int lane = tid & 63;
    const int wave = tid >> 6;
    const int wm = wave >> 1, wn = wave & 1;    // 2x2 waves of 32x32
    const int g = lane >> 4, r = lane & 15;
    const int n0 = (b & 3) * 64;
    const int m0 = dst0 + (b >> 2) * 64;

    const int srow = tid >> 2;
    const int sc   = (tid & 3) * 16;

    const size_t a_off = (size_t)(m0 + srow) * KPAD + sc;
    const size_t b_off = (size_t)(n0 + srow) * KPAD + sc;

    f32x4 acc[2][2] = {};

    for (int k0 = 0; k0 < KPAD; k0 += 64) {
        *(float4*)&As[srow * LDSW + sc]     = *(const float4*)&A[a_off + k0];
        *(float4*)&As[srow * LDSW + sc + 8] = *(const float4*)&A[a_off + k0 + 8];
        *(float4*)&Bs[srow * LDSW + sc]     = *(const float4*)&Wt[b_off + k0];
        *(float4*)&Bs[srow * LDSW + sc + 8] = *(const float4*)&Wt[b_off + k0 + 8];
        __syncthreads();

        #pragma unroll
        for (int kh = 0; kh < 2; ++kh) {
            const bf16x8 af0 = *(const bf16x8*)&As[(wm * 32 +      r) * LDSW + kh * 32 + g * 8];
            const bf16x8 af1 = *(const bf16x8*)&As[(wm * 32 + 16 + r) * LDSW + kh * 32 + g * 8];
            const bf16x8 bf0 = *(const bf16x8*)&Bs[(wn * 32 +      r) * LDSW + kh * 32 + g * 8];
            const bf16x8 bf1 = *(const bf16x8*)&Bs[(wn * 32 + 16 + r) * LDSW + kh * 32 + g * 8];

            acc[0][0] = __builtin_amdgcn_mfma_f32_16x16x32_bf16(af0, bf0, acc[0][0], 0, 0, 0);
            acc[0][1] = __builtin_amdgcn_mfma_f32_16x16x32_bf16(af0, bf1, acc[0][1], 0, 0, 0);
            acc[1][0] = __builtin_amdgcn_mfma_f32_16x16x32_bf16(af1, bf0, acc[1][0], 0, 0, 0);
            acc[1][1] = __builtin_amdgcn_mfma_f32_16x16x32_bf16(af1, bf1, acc[1][1], 0, 0, 0);
        }
        __syncthreads();
    }

    // C/D layout (m89-verified): col = lane&15, row = (lane>>4)*4 + j
    #pragma unroll
    for (int mh = 0; mh < 2; ++mh)
        #pragma unroll
        for (int nh = 0; nh < 2; ++nh) {
            const int col = n0 + wn * 32 + nh * 16 + r;
            const float bv = bias[col];
            #pragma unroll
            for (int j = 0; j < 4; ++j) {
                const int row = m0 + wm * 32 + mh * 16 + g * 4 + j;
                h[(size_t)row * N_HIDDEN + col] = fmaxf(acc[mh][nh][j] + bv, 0.f);
            }
        }
}

// ---------------------------------------------------------------------------
// combo kernel: [0,nw) wprep | [nw,nw+ng) gemm(gemm_dst0) | rest agg(agg_dst0)
// ---------------------------------------------------------------------------
__global__ __launch_bounds__(256) void combo_kernel(
    const float* __restrict__ x,
    const int* __restrict__ idx0,
    const float* __restrict__ Ws0,
    const float* __restrict__ Wn0,
    const float* __restrict__ b0,
    __hip_bfloat16* __restrict__ A,
    __hip_bfloat16* __restrict__ Wt,
    float* __restrict__ h,
    int nw, int ng, int gemm_dst0, int agg_dst0)
{
    __shared__ __align__(16) char sm[SMBYTES];
    int b = blockIdx.x;
    if (b < nw) { wprep_role(b, sm, Ws0, Wn0, Wt); return; }
    b -= nw;
    if (b < ng) { gemm_role(b, gemm_dst0, sm, A, Wt, b0, h); return; }
    b -= ng;
    agg_role(b, agg_dst0, sm, x, idx0, A);
}

// ---------------------------------------------------------------------------
// tail: out[d] = h[d]@Ws1 + (mean_10 h[idx1])@Wn1 + b1.  4 dsts per block.
// ---------------------------------------------------------------------------
__global__ __launch_bounds__(256) void tail_kernel(
    const float* __restrict__ h,
    const int* __restrict__ idx1,
    const float* __restrict__ Ws,     // [256][41]
    const float* __restrict__ Wn,     // [256][41]
    const float* __restrict__ b,      // [41]
    float* __restrict__ out)          // [1024][41]
{
    const int w = threadIdx.x >> 6;
    const int lane = threadIdx.x & 63;
    const int d = blockIdx.x * 4 + w;

    __shared__ float hd[4][N_HIDDEN];
    __shared__ float hn[4][N_HIDDEN];
    __shared__ int sidx[4][FAN1];
    if (lane < FAN1) sidx[w][lane] = idx1[d * FAN1 + lane];
    __syncthreads();

    {
        const int k0 = lane * 4;
        const float4 self = *(const float4*)&h[(size_t)d * N_HIDDEN + k0];
        float ax = 0.f, ay = 0.f, az = 0.f, aw = 0.f;
        #pragma unroll
        for (int i = 0; i < FAN1; ++i) {
            const float4 v = *(const float4*)&h[(size_t)sidx[w][i] * N_HIDDEN + k0];
            ax += v.x; ay += v.y; az += v.z; aw += v.w;
        }
        *(float4*)&hd[w][k0] = self;
        hn[w][k0 + 0] = ax * (1.0f / FAN1);
        hn[w][k0 + 1] = ay * (1.0f / FAN1);
        hn[w][k0 + 2] = az * (1.0f / FAN1);
        hn[w][k0 + 3] = aw * (1.0f / FAN1);
    }
    __syncthreads();

    if (lane < N_CLASSES) {
        const int n = lane;
        float a0 = b[n], a1 = 0.f, a2 = 0.f, a3 = 0.f;
        #pragma unroll 4
        for (int k = 0; k < N_HIDDEN; k += 4) {
            a0 += hd[w][k + 0] * Ws[(k + 0) * N_CLASSES + n] + hn[w][k + 0] * Wn[(k + 0) * N_CLASSES + n];
            a1 += hd[w][k + 1] * Ws[(k + 1) * N_CLASSES + n] + hn[w][k + 1] * Wn[(k + 1) * N_CLASSES + n];
            a2 += hd[w][k + 2] * Ws[(k + 2) * N_CLASSES + n] + hn[w][k + 2] * Wn[(k + 2) * N_CLASSES + n];
            a3 += hd[w][k + 3] * Ws[(k + 3) * N_CLASSES + n] + hn[w][k + 3] * Wn[(k + 3) * N_CLASSES + n];
        }
        out[(size_t)d * N_CLASSES + n] = a0 + a1 + a2 + a3;
    }
}

// ---------------------------------------------------------------------------
extern "C" void kernel_launch(void* const* d_in, const int* in_sizes, int n_in,
                              void* d_out, int out_size, void* d_ws, size_t ws_size,
                              hipStream_t stream) {
    const float* x       = (const float*)d_in[0];
    const float* Wself0  = (const float*)d_in[1];
    const float* Wneigh0 = (const float*)d_in[2];
    const float* b0      = (const float*)d_in[3];
    const float* Wself1  = (const float*)d_in[4];
    const float* Wneigh1 = (const float*)d_in[5];
    const float* b1      = (const float*)d_in[6];
    const int*   idx0    = (const int*)d_in[7];
    const int*   idx1    = (const int*)d_in[8];
    float* out = (float*)d_out;

    // ws: A bf16 [11264*1216] (27.4MB) | Wt bf16 [256*1216] (623KB) | h f32 (11.5MB)
    __hip_bfloat16* A  = (__hip_bfloat16*)d_ws;
    __hip_bfloat16* Wt = A + (size_t)N_DST0 * KPAD;
    float*          h  = (float*)(Wt + (size_t)N_HIDDEN * KPAD);

    // K1: wprep || agg(chunk 0)
    combo_kernel<<<NW + NAC, 256, 0, stream>>>(
        x, idx0, Wself0, Wneigh0, b0, A, Wt, h, NW, 0, 0, 0);
    // K2..K4: gemm(chunk c-1) || agg(chunk c)
    for (int c = 1; c < NCHUNK; ++c)
        combo_kernel<<<NGC + NAC, 256, 0, stream>>>(
            x, idx0, Wself0, Wneigh0, b0, A, Wt, h,
            0, NGC, (c - 1) * CH, c * CH);
    // K5: gemm(chunk 3)
    combo_kernel<<<NGC, 256, 0, stream>>>(
        x, idx0, Wself0, Wneigh0, b0, A, Wt, h, 0, NGC, (NCHUNK - 1) * CH, 0);
    // K6: tail
    tail_kernel<<<N_DST1 / 4, 256, 0, stream>>>(h, idx1, Wself1, Wneigh1, b1, out);
}